// Round 1
// baseline (327.975 us; speedup 1.0000x reference)
//
#include <hip/hip_runtime.h>
#include <math.h>

// ---- problem constants ----
#define DIMC   256
#define HID    680
#define CHN    1360
#define HP     14
#define WP     14
#define P      196
#define POSI   4
#define INTER  64
#define BATCH  64
#define KPAD   704          // 680 padded to 22*32
#define OUTCH  12240        // CHN*9
#define MW     1408         // per-k-plane channel pad
#define MTOT   12672        // 9*MW
#define KIM    576          // INTER*9
#define MPADIN 1408         // 1360 padded to 11*128
#define EPSLN  1e-5f

typedef __attribute__((ext_vector_type(8))) short short8;
typedef __attribute__((ext_vector_type(4))) short short4v;
typedef __attribute__((ext_vector_type(4))) float f32x4;

// ---- workspace layout (bytes) ----
#define OFS_WBIN  0u                  // 1408*256*2   = 720896
#define OFS_WBOUT 720896u             // 256*704*2    = 360448
#define OFS_XT    1081344u            // 64*196*256*2 = 6422528
#define OFS_ABUF  7503872u            // 12544*4 (stage0 out)
#define OFS_A2    7554048u            // 12544*4
#define OFS_A3    7604224u            // 12544*4
#define OFS_BAR   7654400u            // 256 B: bar u32 at +0, stats f32[4] at +16
#define OFS_WGTT  7654656u            // 196*9*1360*2 = 4798080
#define OFS_H1T   12452736u           // 64*196*1360*2 = 34127872
#define OFS_HGT   46580608u           // 64*196*704*2  = 17661952
#define OFS_IMC   64242560u           // 196*576*2     = 225792
#define OFS_WFB   64468352u           // 9*1408*576*2  = 14598144 (end ~79.1MB)

__device__ __forceinline__ unsigned short f2bf(float f) {
    union { float f; unsigned u; } v; v.f = f;
    unsigned u = v.u;
    return (unsigned short)((u + 0x7FFFu + ((u >> 16) & 1u)) >> 16);   // RNE
}
__device__ __forceinline__ float bf2f(unsigned short h) {
    union { unsigned u; float f; } v; v.u = ((unsigned)h) << 16; return v.f;
}

// async 16B global->LDS (wave-uniform LDS base + lane*16; global src may be per-lane)
__device__ __forceinline__ void gl2lds16(const unsigned short* g, unsigned short* l) {
    __builtin_amdgcn_global_load_lds(
        (const __attribute__((address_space(1))) unsigned int*)g,
        (__attribute__((address_space(3))) unsigned int*)l, 16, 0, 0);
}
// BK=64 tile: row stride 64, 8 slots of 16B, logical piece lp in 0..7
__device__ __forceinline__ short8 fragld64(const unsigned short* S, int row, int lp) {
    int slot = ((row >> 1) + lp) & 7;
    return *(const short8*)(S + row * 64 + slot * 8);
}

__device__ __forceinline__ void block_reduce2(float& s, float& ss, float* red, int tid, int nthreads) {
    #pragma unroll
    for (int off = 32; off > 0; off >>= 1) {
        s  += __shfl_down(s, off);
        ss += __shfl_down(ss, off);
    }
    int wid = tid >> 6, nw = nthreads >> 6;
    if ((tid & 63) == 0) { red[wid*2] = s; red[wid*2+1] = ss; }
    __syncthreads();
    if (tid == 0) {
        float S = 0.f, SS = 0.f;
        for (int i = 0; i < nw; i++) { S += red[i*2]; SS += red[i*2+1]; }
        red[0] = S; red[1] = SS;
    }
    __syncthreads();
    s = red[0]; ss = red[1];
}

// device-scope subset barrier for the 49-block wgen kernel (co-resident by construction)
__device__ __forceinline__ void gbar(unsigned int* bar, unsigned int target) {
    __threadfence();                       // release: drain + make this CU's writes visible
    __syncthreads();
    if (threadIdx.x == 0) {
        __hip_atomic_fetch_add(bar, 1u, __ATOMIC_ACQ_REL, __HIP_MEMORY_SCOPE_AGENT);
        while (__hip_atomic_load(bar, __ATOMIC_ACQUIRE, __HIP_MEMORY_SCOPE_AGENT) < target)
            __builtin_amdgcn_s_sleep(2);
    }
    __syncthreads();
    __threadfence();                       // acquire: invalidate so fresh data is visible
}

// ================= fused preamble: casts + x-transpose + wf transpose/cast + stage0 =====
#define NWIN  (MPADIN*DIMC)
#define NWOUT (DIMC*KPAD)
#define PRE_CAST_BLKS 2112
#define PRE_XT_BLKS   512
#define PRE_WF_BLKS   7128        // 9*1408*576/4/256

__global__ __launch_bounds__(256) void k_pre(const float* __restrict__ Win,
                                             const float* __restrict__ Wout,
                                             const float* __restrict__ x,
                                             const float* __restrict__ wf,
                                             const float* __restrict__ posi,
                                             const float* __restrict__ w0,
                                             const float* __restrict__ g0,
                                             const float* __restrict__ b0,
                                             unsigned short* __restrict__ Wbin,
                                             unsigned short* __restrict__ Wbout,
                                             unsigned short* __restrict__ Xt,
                                             unsigned short* __restrict__ wfb,
                                             float* __restrict__ a_out,
                                             unsigned int* __restrict__ bar,
                                             float* __restrict__ stats) {
    __shared__ __align__(16) float smem[14336];      // 56 KB, unioned across segments
    int bid = blockIdx.x, tid = threadIdx.x;
    if (bid < PRE_CAST_BLKS) {
        int i = bid * 256 + tid;
        if (i < NWIN) {
            Wbin[i] = (i < CHN * DIMC) ? f2bf(Win[i]) : (unsigned short)0;
        } else {
            int j = i - NWIN;
            int o = j / KPAD, k = j - o * KPAD;
            Wbout[j] = f2bf(k < HID ? Wout[o * HID + k] : 0.f);
        }
    } else if (bid < PRE_CAST_BLKS + PRE_XT_BLKS) {
        int b2 = bid - PRE_CAST_BLKS;
        int b = b2 >> 3, c0 = (b2 & 7) * 32;
        float (*xs)[197] = (float(*)[197])smem;
        for (int i = tid; i < 32 * P; i += 256) {
            int ci = i / P, pp = i - ci * P;
            xs[ci][pp] = x[((size_t)b * DIMC + c0 + ci) * P + pp];
        }
        __syncthreads();
        for (int j = tid; j < P * 32; j += 256) {
            int ci = j & 31, pp = j >> 5;
            Xt[((size_t)b * P + pp) * DIMC + c0 + ci] = f2bf(xs[ci][pp]);
        }
    } else if (bid < PRE_CAST_BLKS + PRE_XT_BLKS + PRE_WF_BLKS) {
        // wf [12240][576] f32  ->  wfb [9][1408][576] bf16 (pad rows zeroed)
        int t = (bid - PRE_CAST_BLKS - PRE_XT_BLKS) * 256 + tid;
        int j = t * 4;
        int rowi = j / KIM, q = j - rowi * KIM;
        int kk = rowi / MW, ch = rowi - kk * MW;
        short4v sv = (short4v)0;
        if (ch < CHN) {
            float4 v = *(const float4*)(wf + ((size_t)(ch * 9 + kk)) * KIM + q);
            sv[0] = (short)f2bf(v.x); sv[1] = (short)f2bf(v.y);
            sv[2] = (short)f2bf(v.z); sv[3] = (short)f2bf(v.w);
        }
        *(short4v*)(wfb + j) = sv;
    } else {
        // ---- stage0: conv(posi,w0) + LN + relu, single block; also zero bar/stats ----
        if (tid == 0) *bar = 0u;
        if (tid >= 4 && tid < 8) stats[tid - 4] = 0.f;
        float (*ppad)[16][16] = (float(*)[16][16])smem;          // 4*256 floats
        float* tarr = smem + 1024;                               // 12544 floats
        float* red  = smem + 13568;                              // 16 floats
        for (int i = tid; i < POSI * 256; i += 256) {
            int cc = i >> 8, r = i & 255, ly = r >> 4, lx = r & 15;
            float v = 0.f;
            if (ly >= 1 && ly <= HP && lx >= 1 && lx <= WP) v = posi[cc*P + (ly-1)*WP + (lx-1)];
            ppad[cc][ly][lx] = v;
        }
        __syncthreads();
        float s = 0.f, ss = 0.f;
        for (int idx = tid; idx < INTER * P; idx += 256) {
            int cc = idx / P, p = idx - cc*P, yy = p / WP, xx = p - (p/WP)*WP;
            float acc = 0.f;
            #pragma unroll
            for (int ci = 0; ci < POSI; ci++)
                #pragma unroll
                for (int dy = 0; dy < 3; dy++)
                    #pragma unroll
                    for (int dx = 0; dx < 3; dx++)
                        acc += w0[((cc*POSI + ci)*3 + dy)*3 + dx] * ppad[ci][yy+dy][xx+dx];
            tarr[idx] = acc; s += acc; ss += acc*acc;
        }
        block_reduce2(s, ss, red, tid, 256);
        float mu = s / (float)(INTER*P);
        float var = ss / (float)(INTER*P) - mu*mu;
        float rstd = rsqrtf(var + EPSLN);
        for (int idx = tid; idx < INTER * P; idx += 256) {
            float v = (tarr[idx] - mu) * rstd * g0[idx] + b0[idx];
            a_out[idx] = v > 0.f ? v : 0.f;
        }
    }
}

// ============== fused weight-generator: conv1+ln1+conv2+ln2+im2col, 49 blocks ==========
__global__ __launch_bounds__(256) void k_wgen(const float* __restrict__ a_in,
                                              const float* __restrict__ w1,
                                              const float* __restrict__ g1,
                                              const float* __restrict__ b1,
                                              const float* __restrict__ w2,
                                              const float* __restrict__ g2,
                                              const float* __restrict__ b2,
                                              float* __restrict__ a2,
                                              float* __restrict__ a3,
                                              unsigned short* __restrict__ imc,
                                              float* __restrict__ stats,
                                              unsigned int* __restrict__ bar) {
    __shared__ __align__(16) float as[INTER][16][16];            // 64 KB
    __shared__ float red[16];
    const float inv = 1.f / (float)(INTER * P);
    int tid = threadIdx.x;
    int gid = blockIdx.x * 256 + tid;                            // 0..12543
    int c = gid / P, pp = gid - c * P, y = pp / WP, x = pp - (pp / WP) * WP;

    // ---------- layer 1: conv ----------
    for (int i = tid; i < INTER * 256; i += 256) {
        int ci = i >> 8, r = i & 255, ly = r >> 4, lx = r & 15;
        float val = 0.f;
        if (ly >= 1 && ly <= HP && lx >= 1 && lx <= WP) val = a_in[ci*P + (ly-1)*WP + (lx-1)];
        as[ci][ly][lx] = val;
    }
    __syncthreads();
    float v = 0.f;
    for (int ci = 0; ci < INTER; ci++) {
        const float* wr = w1 + (c*INTER + ci)*9;
        v += wr[0]*as[ci][y  ][x] + wr[1]*as[ci][y  ][x+1] + wr[2]*as[ci][y  ][x+2]
           + wr[3]*as[ci][y+1][x] + wr[4]*as[ci][y+1][x+1] + wr[5]*as[ci][y+1][x+2]
           + wr[6]*as[ci][y+2][x] + wr[7]*as[ci][y+2][x+1] + wr[8]*as[ci][y+2][x+2];
    }
    {   // global LN stats
        float s = v, ss = v * v;
        block_reduce2(s, ss, red, tid, 256);
        if (tid == 0) { atomicAdd(&stats[0], s); atomicAdd(&stats[1], ss); }
    }
    gbar(bar, 49);
    {
        float mu = stats[0] * inv;
        float var = stats[1] * inv - mu * mu;
        float rstd = rsqrtf(var + EPSLN);
        float a = (v - mu) * rstd * g1[gid] + b1[gid];
        a2[gid] = a > 0.f ? a : 0.f;
    }
    gbar(bar, 98);

    // ---------- layer 2: conv ----------
    for (int i = tid; i < INTER * 256; i += 256) {
        int ci = i >> 8, r = i & 255, ly = r >> 4, lx = r & 15;
        float val = 0.f;
        if (ly >= 1 && ly <= HP && lx >= 1 && lx <= WP) val = a2[ci*P + (ly-1)*WP + (lx-1)];
        as[ci][ly][lx] = val;
    }
    __syncthreads();
    v = 0.f;
    for (int ci = 0; ci < INTER; ci++) {
        const float* wr = w2 + (c*INTER + ci)*9;
        v += wr[0]*as[ci][y  ][x] + wr[1]*as[ci][y  ][x+1] + wr[2]*as[ci][y  ][x+2]
           + wr[3]*as[ci][y+1][x] + wr[4]*as[ci][y+1][x+1] + wr[5]*as[ci][y+1][x+2]
           + wr[6]*as[ci][y+2][x] + wr[7]*as[ci][y+2][x+1] + wr[8]*as[ci][y+2][x+2];
    }
    {
        float s = v, ss = v * v;
        block_reduce2(s, ss, red, tid, 256);
        if (tid == 0) { atomicAdd(&stats[2], s); atomicAdd(&stats[3], ss); }
    }
    gbar(bar, 147);
    {
        float mu = stats[2] * inv;
        float var = stats[3] * inv - mu * mu;
        float rstd = rsqrtf(var + EPSLN);
        float a = (v - mu) * rstd * g2[gid] + b2[gid];
        a3[gid] = a > 0.f ? a : 0.f;
    }
    gbar(bar, 196);

    // ---------- im2col: a3 [64][196] -> imc [196][576] bf16 ----------
    for (int idx = gid; idx < P * KIM; idx += INTER * P) {
        int p = idx / KIM, q = idx - p * KIM;
        int ci = q / 9, k = q - ci * 9;
        int yy = p / WP + k / 3 - 1, xx = p % WP + k % 3 - 1;
        float vv = 0.f;
        if (yy >= 0 && yy < HP && xx >= 0 && xx < WP) vv = a3[ci * P + yy * WP + xx];
        imc[idx] = f2bf(vv);
    }
}

// ======== final conv as tiled MFMA GEMM, A = pre-cast bf16 wfb[kk][ch][576], BK=64 ======
__global__ __launch_bounds__(256) void k_gemm_wf(const unsigned short* __restrict__ wfb,
                                                 const unsigned short* __restrict__ imc,
                                                 unsigned short* __restrict__ wgtT) {
    __shared__ __align__(16) unsigned short buf[64*64 + 208*64];   // 34 KB
    unsigned short* As = buf;                                      // 64 rows x 64
    unsigned short* Bs = buf + 64*64;                              // 208 rows x 64
    unsigned short* ot = buf;                                      // reused after K-loop
    int tid = threadIdx.x;
    int w = tid >> 6, lane = tid & 63, quad = lane >> 4, c16 = lane & 15;
    int m0 = blockIdx.x * 64;                                      // 198 blocks
    int kk = m0 / MW, ch0 = m0 - kk * MW;
    for (int i = tid; i < 96; i += 256)                            // zero B pad rows 196..207
        *(short8*)(Bs + 196 * 64 + i * 8) = (short8)0;
    f32x4 acc[13];
    #pragma unroll
    for (int f = 0; f < 13; f++) acc[f] = (f32x4)0.f;

    for (int kc = 0; kc < 9; ++kc) {                               // K=576, chunks of 64
        int k0 = kc * 64;
        if (kc) __syncthreads();
        #pragma unroll
        for (int i = tid; i < 512; i += 256) {                     // A: 64 rows x 8 pieces
            int r = i >> 3, s = i & 7, q = (s - (r >> 1)) & 7;
            gl2lds16(wfb + ((size_t)(kk * MW + ch0 + r)) * KIM + k0 + q * 8, As + (i & ~63) * 8);
        }
        for (int i = tid; i < 1568; i += 256) {                    // B: 196 rows x 8 pieces
            int r = i >> 3, s = i & 7, q = (s - (r >> 1)) & 7;
            gl2lds16(imc + (size_t)r * KIM + k0 + q * 8, Bs + (i & ~63) * 8);
        }
        __syncthreads();
        #pragma unroll
        for (int ks = 0; ks < 2; ++ks) {
            short8 af = fragld64(As, w * 16 + c16, ks * 4 + quad);
            #pragma unroll
            for (int f = 0; f < 13; f++) {
                short8 bf = fragld64(Bs, f * 16 + c16, ks * 4 + quad);
                acc[f] = __builtin_amdgcn_mfma_f32_16x16x32_bf16(af, bf, acc[f], 0, 0, 0);
            }
        }
    }
    __syncthreads();
    #pragma unroll
    for (int f = 0; f < 13; f++) {
        int p = f * 16 + c16;
        if (p < P) {
            short4v sv;
            sv[0] = (short)f2bf(acc[f][0]);
            sv[1] = (short)f2bf(acc[f][1]);
            sv[2] = (short)f2bf(acc[f][2]);
            sv[3] = (short)f2bf(acc[f][3]);
            *(short4v*)(ot + p * 72 + w * 16 + quad * 4) = sv;
        }
    }
    __syncthreads();
    int nvalid = CHN - ch0; if (nvalid > 64) nvalid = 64;
    for (int p = tid; p < P; p += 256) {
        const short8* src = (const short8*)(ot + p * 72);
        unsigned short* dst = wgtT + ((size_t)p * 9 + kk) * CHN + ch0;
        #pragma unroll
        for (int j = 0; j < 8; j++)
            if (j * 8 < nvalid) *(short8*)(dst + j * 8) = src[j];
    }
}

// ---------------- tiled MFMA GEMM 1 (BK=64): h1t[n][m] = sum_k Wbin[m][k] Xt[n][k] --------
__global__ __launch_bounds__(256) void k_gemm_in(const unsigned short* __restrict__ A,
                                                 const unsigned short* __restrict__ B,
                                                 unsigned short* __restrict__ C) {
    __shared__ __align__(16) unsigned short As[128 * 64];    // 16 KB
    __shared__ __align__(16) unsigned short Bs[128 * 64];    // 16 KB
    int tid = threadIdx.x;
    int w = tid >> 6, lane = tid & 63, quad = lane >> 4, c16 = lane & 15;
    int m0 = blockIdx.x * 128, n0 = blockIdx.y * 128;
    int wm = (w & 1) * 64, wn = (w >> 1) * 64;
    f32x4 acc[4][4];
    #pragma unroll
    for (int i = 0; i < 4; i++)
        #pragma unroll
        for (int j = 0; j < 4; j++) acc[i][j] = (f32x4)0.f;

    for (int kc = 0; kc < 4; ++kc) {                         // K=256, chunks of 64
        int k0 = kc * 64;
        if (kc) __syncthreads();
        #pragma unroll
        for (int i = tid; i < 1024; i += 256) {              // A: 128 rows x 8 pieces
            int r = i >> 3, s = i & 7, q = (s - (r >> 1)) & 7;
            gl2lds16(A + (size_t)(m0 + r) * DIMC + k0 + q * 8, As + (i & ~63) * 8);
        }
        #pragma unroll
        for (int i = tid; i < 1024; i += 256) {              // B: 128 rows x 8 pieces
            int r = i >> 3, s = i & 7, q = (s - (r >> 1)) & 7;
            gl2lds16(B + (size_t)(n0 + r) * DIMC + k0 + q * 8, Bs + (i & ~63) * 8);
        }
        __syncthreads();
        #pragma unroll
        for (int ks = 0; ks < 2; ++ks) {
            short8 af[4], bfr[4];
            #pragma unroll
            for (int i = 0; i < 4; i++) af[i] = fragld64(As, wm + i * 16 + c16, ks * 4 + quad);
            #pragma unroll
            for (int j = 0; j < 4; j++) bfr[j] = fragld64(Bs, wn + j * 16 + c16, ks * 4 + quad);
            #pragma unroll
            for (int i = 0; i < 4; i++)
                #pragma unroll
                for (int j = 0; j < 4; j++)
                    acc[i][j] = __builtin_amdgcn_mfma_f32_16x16x32_bf16(af[i], bfr[j], acc[i][j], 0, 0, 0);
        }
    }
    #pragma unroll
    for (int j = 0; j < 4; j++) {
        int n = n0 + wn + j * 16 + c16;
        unsigned short* dst = C + (size_t)n * CHN;
        #pragma unroll
        for (int i = 0; i < 4; i++) {
            int m = m0 + wm + i * 16 + quad * 4;
            if (m < CHN) {
                short4v sv;
                sv[0] = (short)f2bf(acc[i][j][0]);
                sv[1] = (short)f2bf(acc[i][j][1]);
                sv[2] = (short)f2bf(acc[i][j][2]);
                sv[3] = (short)f2bf(acc[i][j][3]);
                *(short4v*)(dst + m) = sv;
            }
        }
    }
}

// ---------------- fused tvconv + gelu-gate: XCD-affinity swizzled grid ----------------
__global__ __launch_bounds__(256) void k_tvg(const unsigned short* __restrict__ h1t,
                                             const unsigned short* __restrict__ wgtT,
                                             unsigned short* __restrict__ hgt) {
    __shared__ __align__(16) unsigned short wl[9 * CHN];   // 24480 B, [k][CHN]
    int id = blockIdx.x;
    int xcd = id & 7, q = id >> 3;
    int p = xcd * 25 + (q % 25);
    int bg = q / 25;
    if (p >= P) return;
    int b0 = bg * 16, tid = threadIdx.x;
    const unsigned short* wrow = wgtT + (size_t)p * 9 * CHN;
    for (int i = tid * 8; i < 9 * CHN; i += 256 * 8)
        *(short8*)(wl + i) = *(const short8*)(wrow + i);
    int y = p / WP, x = p - (p / WP) * WP;
    int pn[9]; bool pv[9];
    #pragma unroll
    for (int k = 0; k < 9; k++) {
        int yy = y + k / 3 - 1, xx = x + (k % 3) - 1;
        pv[k] = (yy >= 0 && yy < HP && xx >= 0 && xx < WP);
        pn[k] = pv[k] ? yy * WP + xx : 0;
    }
    __syncthreads();
    for (int j = tid; j < 16 * 85; j += 256) {
        int bl = j / 85, c = (j - bl * 85) * 8;
        int b = b0 + bl;
        const unsigned short* hb = h1t + (size_t)b * P * CHN;
        float s1[8], s2[8];
        #pragma unroll
        for (int e = 0; e < 8; e++) { s1[e] = 0.f; s2[e] = 0.f; }
        #pragma unroll
        for (int k = 0; k < 9; k++) {
            if (!pv[k]) continue;
            const unsigned short* hr = hb + (size_t)pn[k] * CHN + c;
            short8 h1v = *(const short8*)hr;
            short8 h2v = *(const short8*)(hr + HID);
            short8 w1v = *(const short8*)(wl + k * CHN + c);
            short8 w2v = *(const short8*)(wl + k * CHN + HID + c);
            #pragma unroll
            for (int e = 0; e < 8; e++) {
                s1[e] += bf2f((unsigned short)w1v[e]) * bf2f((unsigned short)h1v[e]);
                s2[e] += bf2f((unsigned short)w2v[e]) * bf2f((unsigned short)h2v[e]);
            }
        }
        short8 o;
        #pragma unroll
        for (int e = 0; e < 8; e++) {
            float gl = 0.5f * s1[e] * (1.f + erff(s1[e] * 0.70710678118654752f));
            o[e] = (short)f2bf(gl * s2[e]);
        }
        *(short8*)(hgt + ((size_t)b * P + p) * KPAD + c) = o;
    }
    if (tid < 48) {
        int bl = tid / 3, z = (tid - bl * 3) * 8;
        *(short8*)(hgt + ((size_t)(b0 + bl) * P + p) * KPAD + HID + z) = (short8)0;
    }
}

// ---------------- tiled MFMA GEMM 2 (BK=64): out[m][n] = sum_k Wbout[m][k] hgt[n][k] ------
__global__ __launch_bounds__(256) void k_gemm_out(const unsigned short* __restrict__ A,
                                                  const unsigned short* __restrict__ B,
                                                  float* __restrict__ out) {
    __shared__ __align__(16) unsigned short As[64 * 64];     // 8 KB
    __shared__ __align__(16) unsigned short Bs[128 * 64];    // 16 KB
    int tid = threadIdx.x;
    int w = tid >> 6, lane = tid & 63, quad = lane >> 4, c16 = lane & 15;
    int m0 = blockIdx.x * 64, n0 = blockIdx.y * 128;
    int wm = (w & 1) * 32, wn = (w >> 1) * 64;
    f32x4 acc[2][4];
    #pragma unroll
    for (int i = 0; i < 2; i++)
        #pragma unroll
        for (int j = 0; j < 4; j++) acc[i][j] = (f32x4)0.f;

    for (int kc = 0; kc < 11; ++kc) {                        // K=704, chunks of 64
        int k0 = kc * 64;
        if (kc) __syncthreads();
        #pragma unroll
        for (int i = tid; i < 512; i += 256) {               // A: 64 rows x 8 pieces
            int r = i >> 3, s = i & 7, q = (s - (r >> 1)) & 7;
            gl2lds16(A + (size_t)(m0 + r) * KPAD + k0 + q * 8, As + (i & ~63) * 8);
        }
        #pragma unroll
        for (int i = tid; i < 1024; i += 256) {              // B: 128 rows x 8 pieces
            int r = i >> 3, s = i & 7, q = (s - (r >> 1)) & 7;
            gl2lds16(B + (size_t)(n0 + r) * KPAD + k0 + q * 8, Bs + (i & ~63) * 8);
        }
        __syncthreads();
        #pragma unroll
        for (int ks = 0; ks < 2; ++ks) {
            short8 af[2], bfr[4];
            #pragma unroll
            for (int i = 0; i < 2; i++) af[i] = fragld64(As, wm + i * 16 + c16, ks * 4 + quad);
            #pragma unroll
            for (int j = 0; j < 4; j++) bfr[j] = fragld64(Bs, wn + j * 16 + c16, ks * 4 + quad);
            #pragma unroll
            for (int i = 0; i < 2; i++)
                #pragma unroll
                for (int j = 0; j < 4; j++)
                    acc[i][j] = __builtin_amdgcn_mfma_f32_16x16x32_bf16(af[i], bfr[j], acc[i][j], 0, 0, 0);
        }
    }
    #pragma unroll
    for (int j = 0; j < 4; j++) {
        int n = n0 + wn + j * 16 + c16;
        int b = n / P, pp = n - b * P;
        #pragma unroll
        for (int i = 0; i < 2; i++) {
            int m = m0 + wm + i * 16 + quad * 4;
            #pragma unroll
            for (int r = 0; r < 4; r++)
                out[((size_t)b * DIMC + m + r) * P + pp] = acc[i][j][r];
        }
    }
}

extern "C" void kernel_launch(void* const* d_in, const int* in_sizes, int n_in,
                              void* d_out, int out_size, void* d_ws, size_t ws_size,
                              hipStream_t stream) {
    (void)in_sizes; (void)n_in; (void)out_size; (void)ws_size;
    const float* x     = (const float*)d_in[0];
    const float* W_in  = (const float*)d_in[1];
    const float* posi  = (const float*)d_in[2];
    const float* w0    = (const float*)d_in[3];
    const float* g0    = (const float*)d_in[4];
    const float* b0    = (const float*)d_in[5];
    const float* w1    = (const float*)d_in[6];
    const float* g1    = (const float*)d_in[7];
    const float* b1    = (const float*)d_in[8];
    const float* w2    = (const float*)d_in[9];
    const float* g2    = (const float*)d_in[10];
    const float* b2    = (const float*)d_in[11];
    const float* wf    = (const float*)d_in[12];
    const float* W_out = (const float*)d_in[13];
    float* out = (float*)d_out;
    char* ws = (char*)d_ws;

    unsigned short* Wbin  = (unsigned short*)(ws + OFS_WBIN);
    unsigned short* Wbout = (unsigned short*)(ws + OFS_WBOUT);
    unsigned short* Xt    = (unsigned short*)(ws + OFS_XT);
    float*          a_buf = (float*)(ws + OFS_ABUF);
    float*          a2    = (float*)(ws + OFS_A2);
    float*          a3    = (float*)(ws + OFS_A3);
    unsigned int*   bar   = (unsigned int*)(ws + OFS_BAR);
    float*          stats = (float*)(ws + OFS_BAR + 16);
    unsigned short* wgtT  = (unsigned short*)(ws + OFS_WGTT);
    unsigned short* h1t   = (unsigned short*)(ws + OFS_H1T);
    unsigned short* hgt   = (unsigned short*)(ws + OFS_HGT);
    unsigned short* imc   = (unsigned short*)(ws + OFS_IMC);
    unsigned short* wfb   = (unsigned short*)(ws + OFS_WFB);

    // 1: fused preamble (casts, x-transpose, wf transpose/cast, stage0, counter init)
    k_pre<<<PRE_CAST_BLKS + PRE_XT_BLKS + PRE_WF_BLKS + 1, 256, 0, stream>>>(
        W_in, W_out, x, wf, posi, w0, g0, b0, Wbin, Wbout, Xt, wfb, a_buf, bar, stats);
    // 2: fused weight-generator chain (spin-barrier global sync, 49 co-resident blocks)
    k_wgen<<<49, 256, 0, stream>>>(a_buf, w1, g1, b1, w2, g2, b2, a2, a3, imc, stats, bar);
    // 3: final conv GEMM (bf16 A, BK=64)
    k_gemm_wf<<<MTOT/64, 256, 0, stream>>>(wfb, imc, wgtT);
    // 4-6: main path
    k_gemm_in <<<dim3(MPADIN/128, (BATCH*P)/128), 256, 0, stream>>>(Wbin, Xt, h1t);
    k_tvg     <<<800, 256, 0, stream>>>(h1t, wgtT, hgt);
    k_gemm_out<<<dim3(DIMC/64, (BATCH*P)/128), 256, 0, stream>>>(Wbout, hgt, out);
}

// Round 2
// 309.262 us; speedup vs baseline: 1.0605x; 1.0605x over previous
//
#include <hip/hip_runtime.h>
#include <math.h>

// ---- problem constants ----
#define DIMC   256
#define HID    680
#define CHN    1360
#define HP     14
#define WP     14
#define P      196
#define POSI   4
#define INTER  64
#define BATCH  64
#define KPAD   704          // 680 padded to 22*32
#define OUTCH  12240        // CHN*9
#define MW     1408         // per-k-plane channel pad
#define MTOT   12672        // 9*MW
#define KIM    576          // INTER*9
#define MPADIN 1408         // 1360 padded to 11*128
#define EPSLN  1e-5f

typedef __attribute__((ext_vector_type(8))) short short8;
typedef __attribute__((ext_vector_type(4))) short short4v;
typedef __attribute__((ext_vector_type(4))) float f32x4;

// ---- workspace layout (bytes) ----
#define OFS_WBIN  0u                  // 1408*256*2   = 720896
#define OFS_WBOUT 720896u             // 256*704*2    = 360448
#define OFS_XT    1081344u            // 64*196*256*2 = 6422528
#define OFS_ABUF  7503872u            // 12544*4 (stage0 out)
#define OFS_V1    7554048u            // 12544*4
#define OFS_V2    7604224u            // 12544*4
#define OFS_STAT  7654400u            // 256 B: stats f32[4] at +0
#define OFS_WGTT  7654656u            // 196*9*1360*2 = 4798080
#define OFS_H1T   12452736u           // 64*196*1360*2 = 34127872
#define OFS_HGT   46580608u           // 64*196*704*2  = 17661952
#define OFS_IMC   64242560u           // 196*576*2     = 225792
#define OFS_WFB   64468352u           // 9*1408*576*2  = 14598144 (end ~79.1MB)

__device__ __forceinline__ unsigned short f2bf(float f) {
    union { float f; unsigned u; } v; v.f = f;
    unsigned u = v.u;
    return (unsigned short)((u + 0x7FFFu + ((u >> 16) & 1u)) >> 16);   // RNE
}
__device__ __forceinline__ float bf2f(unsigned short h) {
    union { unsigned u; float f; } v; v.u = ((unsigned)h) << 16; return v.f;
}

// async 16B global->LDS (wave-uniform LDS base + lane*16; global src may be per-lane)
__device__ __forceinline__ void gl2lds16(const unsigned short* g, unsigned short* l) {
    __builtin_amdgcn_global_load_lds(
        (const __attribute__((address_space(1))) unsigned int*)g,
        (__attribute__((address_space(3))) unsigned int*)l, 16, 0, 0);
}
// BK=64 tile: row stride 64, 8 slots of 16B, logical piece lp in 0..7
__device__ __forceinline__ short8 fragld64(const unsigned short* S, int row, int lp) {
    int slot = ((row >> 1) + lp) & 7;
    return *(const short8*)(S + row * 64 + slot * 8);
}

__device__ __forceinline__ void block_reduce2(float& s, float& ss, float* red, int tid, int nthreads) {
    #pragma unroll
    for (int off = 32; off > 0; off >>= 1) {
        s  += __shfl_down(s, off);
        ss += __shfl_down(ss, off);
    }
    int wid = tid >> 6, nw = nthreads >> 6;
    if ((tid & 63) == 0) { red[wid*2] = s; red[wid*2+1] = ss; }
    __syncthreads();
    if (tid == 0) {
        float S = 0.f, SS = 0.f;
        for (int i = 0; i < nw; i++) { S += red[i*2]; SS += red[i*2+1]; }
        red[0] = S; red[1] = SS;
    }
    __syncthreads();
    s = red[0]; ss = red[1];
}

// ================= fused preamble: casts + x-transpose + wf transpose/cast
//                   + imc zero + stage0 =====
#define NWIN  (MPADIN*DIMC)
#define NWOUT (DIMC*KPAD)
#define PRE_CAST_BLKS 2112
#define PRE_XT_BLKS   512
#define PRE_WF_BLKS   7128        // 9*1408*576/4/256
#define PRE_IMZ_BLKS  56          // zero 225792 B of imc, 16 B/thread

__global__ __launch_bounds__(256) void k_pre(const float* __restrict__ Win,
                                             const float* __restrict__ Wout,
                                             const float* __restrict__ x,
                                             const float* __restrict__ wf,
                                             const float* __restrict__ posi,
                                             const float* __restrict__ w0,
                                             const float* __restrict__ g0,
                                             const float* __restrict__ b0,
                                             unsigned short* __restrict__ Wbin,
                                             unsigned short* __restrict__ Wbout,
                                             unsigned short* __restrict__ Xt,
                                             unsigned short* __restrict__ wfb,
                                             unsigned short* __restrict__ imc,
                                             float* __restrict__ a_out,
                                             float* __restrict__ stats) {
    __shared__ __align__(16) float smem[14336];      // 56 KB, unioned across segments
    int bid = blockIdx.x, tid = threadIdx.x;
    if (bid < PRE_CAST_BLKS) {
        int i = bid * 256 + tid;
        if (i < NWIN) {
            Wbin[i] = (i < CHN * DIMC) ? f2bf(Win[i]) : (unsigned short)0;
        } else {
            int j = i - NWIN;
            int o = j / KPAD, k = j - o * KPAD;
            Wbout[j] = f2bf(k < HID ? Wout[o * HID + k] : 0.f);
        }
    } else if (bid < PRE_CAST_BLKS + PRE_XT_BLKS) {
        int b2 = bid - PRE_CAST_BLKS;
        int b = b2 >> 3, c0 = (b2 & 7) * 32;
        float (*xs)[197] = (float(*)[197])smem;
        for (int i = tid; i < 32 * P; i += 256) {
            int ci = i / P, pp = i - ci * P;
            xs[ci][pp] = x[((size_t)b * DIMC + c0 + ci) * P + pp];
        }
        __syncthreads();
        for (int j = tid; j < P * 32; j += 256) {
            int ci = j & 31, pp = j >> 5;
            Xt[((size_t)b * P + pp) * DIMC + c0 + ci] = f2bf(xs[ci][pp]);
        }
    } else if (bid < PRE_CAST_BLKS + PRE_XT_BLKS + PRE_WF_BLKS) {
        // wf [12240][576] f32  ->  wfb [9][1408][576] bf16 (pad rows zeroed)
        int t = (bid - PRE_CAST_BLKS - PRE_XT_BLKS) * 256 + tid;
        int j = t * 4;
        int rowi = j / KIM, q = j - rowi * KIM;
        int kk = rowi / MW, ch = rowi - kk * MW;
        short4v sv = (short4v)0;
        if (ch < CHN) {
            float4 v = *(const float4*)(wf + ((size_t)(ch * 9 + kk)) * KIM + q);
            sv[0] = (short)f2bf(v.x); sv[1] = (short)f2bf(v.y);
            sv[2] = (short)f2bf(v.z); sv[3] = (short)f2bf(v.w);
        }
        *(short4v*)(wfb + j) = sv;
    } else if (bid < PRE_CAST_BLKS + PRE_XT_BLKS + PRE_WF_BLKS + PRE_IMZ_BLKS) {
        // zero imc so the scatter-im2col only writes in-bounds entries
        int t = (bid - PRE_CAST_BLKS - PRE_XT_BLKS - PRE_WF_BLKS) * 256 + tid;
        if (t < (P * KIM) / 8) *(short8*)(imc + t * 8) = (short8)0;
    } else {
        // ---- stage0: conv(posi,w0) + LN + relu, single block; also zero stats ----
        if (tid < 4) stats[tid] = 0.f;
        float (*ppad)[16][16] = (float(*)[16][16])smem;          // 4*256 floats
        float* tarr = smem + 1024;                               // 12544 floats
        float* red  = smem + 13568;                              // 16 floats
        for (int i = tid; i < POSI * 256; i += 256) {
            int cc = i >> 8, r = i & 255, ly = r >> 4, lx = r & 15;
            float v = 0.f;
            if (ly >= 1 && ly <= HP && lx >= 1 && lx <= WP) v = posi[cc*P + (ly-1)*WP + (lx-1)];
            ppad[cc][ly][lx] = v;
        }
        __syncthreads();
        float s = 0.f, ss = 0.f;
        for (int idx = tid; idx < INTER * P; idx += 256) {
            int cc = idx / P, p = idx - cc*P, yy = p / WP, xx = p - (p/WP)*WP;
            float acc = 0.f;
            #pragma unroll
            for (int ci = 0; ci < POSI; ci++)
                #pragma unroll
                for (int dy = 0; dy < 3; dy++)
                    #pragma unroll
                    for (int dx = 0; dx < 3; dx++)
                        acc += w0[((cc*POSI + ci)*3 + dy)*3 + dx] * ppad[ci][yy+dy][xx+dx];
            tarr[idx] = acc; s += acc; ss += acc*acc;
        }
        block_reduce2(s, ss, red, tid, 256);
        float mu = s / (float)(INTER*P);
        float var = ss / (float)(INTER*P) - mu*mu;
        float rstd = rsqrtf(var + EPSLN);
        for (int idx = tid; idx < INTER * P; idx += 256) {
            float v = (tarr[idx] - mu) * rstd * g0[idx] + b0[idx];
            a_out[idx] = v > 0.f ? v : 0.f;
        }
    }
}

// ---- wgen chain, kernel-boundary sync (no spin barriers) ----
// conv1: a_buf -> v1, partial LN stats -> stats[0..1]
__global__ __launch_bounds__(256) void k_conv1(const float* __restrict__ a_in,
                                               const float* __restrict__ w,
                                               float* __restrict__ v_out,
                                               float* __restrict__ stats) {
    __shared__ __align__(16) float as[INTER][16][16];
    __shared__ float red[16];
    int tid = threadIdx.x;
    for (int i = tid; i < INTER * 256; i += 256) {
        int ci = i >> 8, r = i & 255, ly = r >> 4, lx = r & 15;
        float val = 0.f;
        if (ly >= 1 && ly <= HP && lx >= 1 && lx <= WP) val = a_in[ci*P + (ly-1)*WP + (lx-1)];
        as[ci][ly][lx] = val;
    }
    __syncthreads();
    int gid = blockIdx.x * 256 + tid;
    int c = gid / P, p = gid - c*P, y = p / WP, x = p - (p/WP)*WP;
    float v = 0.f;
    for (int ci = 0; ci < INTER; ci++) {
        const float* wr = w + (c*INTER + ci)*9;
        v += wr[0]*as[ci][y  ][x] + wr[1]*as[ci][y  ][x+1] + wr[2]*as[ci][y  ][x+2]
           + wr[3]*as[ci][y+1][x] + wr[4]*as[ci][y+1][x+1] + wr[5]*as[ci][y+1][x+2]
           + wr[6]*as[ci][y+2][x] + wr[7]*as[ci][y+2][x+1] + wr[8]*as[ci][y+2][x+2];
    }
    v_out[gid] = v;
    float s = v, ss = v * v;
    block_reduce2(s, ss, red, tid, 256);
    if (tid == 0) { atomicAdd(&stats[0], s); atomicAdd(&stats[1], ss); }
}

// conv2: ln1(v1) applied while staging LDS; conv -> v2, stats[2..3]
__global__ __launch_bounds__(256) void k_conv2(const float* __restrict__ v_in,
                                               const float* __restrict__ g,
                                               const float* __restrict__ b,
                                               const float* __restrict__ w,
                                               float* __restrict__ v_out,
                                               float* __restrict__ stats) {
    __shared__ __align__(16) float as[INTER][16][16];
    __shared__ float red[16];
    const float inv = 1.f / (float)(INTER * P);
    int tid = threadIdx.x;
    float mu = stats[0] * inv;
    float var = stats[1] * inv - mu * mu;
    float rstd = rsqrtf(var + EPSLN);
    for (int i = tid; i < INTER * 256; i += 256) {
        int ci = i >> 8, r = i & 255, ly = r >> 4, lx = r & 15;
        float val = 0.f;
        if (ly >= 1 && ly <= HP && lx >= 1 && lx <= WP) {
            int g2 = ci*P + (ly-1)*WP + (lx-1);
            float a = (v_in[g2] - mu) * rstd * g[g2] + b[g2];
            val = a > 0.f ? a : 0.f;
        }
        as[ci][ly][lx] = val;
    }
    __syncthreads();
    int gid = blockIdx.x * 256 + tid;
    int c = gid / P, p = gid - c*P, y = p / WP, x = p - (p/WP)*WP;
    float v = 0.f;
    for (int ci = 0; ci < INTER; ci++) {
        const float* wr = w + (c*INTER + ci)*9;
        v += wr[0]*as[ci][y  ][x] + wr[1]*as[ci][y  ][x+1] + wr[2]*as[ci][y  ][x+2]
           + wr[3]*as[ci][y+1][x] + wr[4]*as[ci][y+1][x+1] + wr[5]*as[ci][y+1][x+2]
           + wr[6]*as[ci][y+2][x] + wr[7]*as[ci][y+2][x+1] + wr[8]*as[ci][y+2][x+2];
    }
    v_out[gid] = v;
    float s = v, ss = v * v;
    block_reduce2(s, ss, red, tid, 256);
    if (tid == 0) { atomicAdd(&stats[2], s); atomicAdd(&stats[3], ss); }
}

// ln2 + scatter-im2col: imc[(p')*576 + ci*9 + k] = relu(ln2(v2[ci][p]))
__global__ __launch_bounds__(256) void k_lnsc(const float* __restrict__ v_in,
                                              const float* __restrict__ g,
                                              const float* __restrict__ b,
                                              const float* __restrict__ stats,
                                              unsigned short* __restrict__ imc) {
    const float inv = 1.f / (float)(INTER * P);
    int gid = blockIdx.x * 256 + threadIdx.x;
    float mu = stats[2] * inv;
    float var = stats[3] * inv - mu * mu;
    float rstd = rsqrtf(var + EPSLN);
    float a = (v_in[gid] - mu) * rstd * g[gid] + b[gid];
    a = a > 0.f ? a : 0.f;
    unsigned short bv = f2bf(a);
    int ci = gid / P, p = gid - ci * P, y = p / WP, x = p - (p / WP) * WP;
    #pragma unroll
    for (int k = 0; k < 9; k++) {
        int yp = y - (k / 3 - 1), xp = x - (k % 3 - 1);
        if (yp >= 0 && yp < HP && xp >= 0 && xp < WP)
            imc[(yp * WP + xp) * KIM + ci * 9 + k] = bv;
    }
}

// ======== final conv as tiled MFMA GEMM, A = pre-cast bf16 wfb[kk][ch][576], BK=64 ======
__global__ __launch_bounds__(256) void k_gemm_wf(const unsigned short* __restrict__ wfb,
                                                 const unsigned short* __restrict__ imc,
                                                 unsigned short* __restrict__ wgtT) {
    __shared__ __align__(16) unsigned short buf[64*64 + 208*64];   // 34 KB
    unsigned short* As = buf;                                      // 64 rows x 64
    unsigned short* Bs = buf + 64*64;                              // 208 rows x 64
    unsigned short* ot = buf;                                      // reused after K-loop
    int tid = threadIdx.x;
    int w = tid >> 6, lane = tid & 63, quad = lane >> 4, c16 = lane & 15;
    int m0 = blockIdx.x * 64;                                      // 198 blocks
    int kk = m0 / MW, ch0 = m0 - kk * MW;
    for (int i = tid; i < 96; i += 256)                            // zero B pad rows 196..207
        *(short8*)(Bs + 196 * 64 + i * 8) = (short8)0;
    f32x4 acc[13];
    #pragma unroll
    for (int f = 0; f < 13; f++) acc[f] = (f32x4)0.f;

    for (int kc = 0; kc < 9; ++kc) {                               // K=576, chunks of 64
        int k0 = kc * 64;
        if (kc) __syncthreads();
        #pragma unroll
        for (int i = tid; i < 512; i += 256) {                     // A: 64 rows x 8 pieces
            int r = i >> 3, s = i & 7, q = (s - (r >> 1)) & 7;
            gl2lds16(wfb + ((size_t)(kk * MW + ch0 + r)) * KIM + k0 + q * 8, As + (i & ~63) * 8);
        }
        for (int i = tid; i < 1568; i += 256) {                    // B: 196 rows x 8 pieces
            int r = i >> 3, s = i & 7, q = (s - (r >> 1)) & 7;
            gl2lds16(imc + (size_t)r * KIM + k0 + q * 8, Bs + (i & ~63) * 8);
        }
        __syncthreads();
        #pragma unroll
        for (int ks = 0; ks < 2; ++ks) {
            short8 af = fragld64(As, w * 16 + c16, ks * 4 + quad);
            #pragma unroll
            for (int f = 0; f < 13; f++) {
                short8 bf = fragld64(Bs, f * 16 + c16, ks * 4 + quad);
                acc[f] = __builtin_amdgcn_mfma_f32_16x16x32_bf16(af, bf, acc[f], 0, 0, 0);
            }
        }
    }
    __syncthreads();
    #pragma unroll
    for (int f = 0; f < 13; f++) {
        int p = f * 16 + c16;
        if (p < P) {
            short4v sv;
            sv[0] = (short)f2bf(acc[f][0]);
            sv[1] = (short)f2bf(acc[f][1]);
            sv[2] = (short)f2bf(acc[f][2]);
            sv[3] = (short)f2bf(acc[f][3]);
            *(short4v*)(ot + p * 72 + w * 16 + quad * 4) = sv;
        }
    }
    __syncthreads();
    int nvalid = CHN - ch0; if (nvalid > 64) nvalid = 64;
    for (int p = tid; p < P; p += 256) {
        const short8* src = (const short8*)(ot + p * 72);
        unsigned short* dst = wgtT + ((size_t)p * 9 + kk) * CHN + ch0;
        #pragma unroll
        for (int j = 0; j < 8; j++)
            if (j * 8 < nvalid) *(short8*)(dst + j * 8) = src[j];
    }
}

// ---------------- tiled MFMA GEMM 1 (BK=64): h1t[n][m] = sum_k Wbin[m][k] Xt[n][k] --------
__global__ __launch_bounds__(256) void k_gemm_in(const unsigned short* __restrict__ A,
                                                 const unsigned short* __restrict__ B,
                                                 unsigned short* __restrict__ C) {
    __shared__ __align__(16) unsigned short As[128 * 64];    // 16 KB
    __shared__ __align__(16) unsigned short Bs[128 * 64];    // 16 KB
    int tid = threadIdx.x;
    int w = tid >> 6, lane = tid & 63, quad = lane >> 4, c16 = lane & 15;
    int m0 = blockIdx.x * 128, n0 = blockIdx.y * 128;
    int wm = (w & 1) * 64, wn = (w >> 1) * 64;
    f32x4 acc[4][4];
    #pragma unroll
    for (int i = 0; i < 4; i++)
        #pragma unroll
        for (int j = 0; j < 4; j++) acc[i][j] = (f32x4)0.f;

    for (int kc = 0; kc < 4; ++kc) {                         // K=256, chunks of 64
        int k0 = kc * 64;
        if (kc) __syncthreads();
        #pragma unroll
        for (int i = tid; i < 1024; i += 256) {              // A: 128 rows x 8 pieces
            int r = i >> 3, s = i & 7, q = (s - (r >> 1)) & 7;
            gl2lds16(A + (size_t)(m0 + r) * DIMC + k0 + q * 8, As + (i & ~63) * 8);
        }
        #pragma unroll
        for (int i = tid; i < 1024; i += 256) {              // B: 128 rows x 8 pieces
            int r = i >> 3, s = i & 7, q = (s - (r >> 1)) & 7;
            gl2lds16(B + (size_t)(n0 + r) * DIMC + k0 + q * 8, Bs + (i & ~63) * 8);
        }
        __syncthreads();
        #pragma unroll
        for (int ks = 0; ks < 2; ++ks) {
            short8 af[4], bfr[4];
            #pragma unroll
            for (int i = 0; i < 4; i++) af[i] = fragld64(As, wm + i * 16 + c16, ks * 4 + quad);
            #pragma unroll
            for (int j = 0; j < 4; j++) bfr[j] = fragld64(Bs, wn + j * 16 + c16, ks * 4 + quad);
            #pragma unroll
            for (int i = 0; i < 4; i++)
                #pragma unroll
                for (int j = 0; j < 4; j++)
                    acc[i][j] = __builtin_amdgcn_mfma_f32_16x16x32_bf16(af[i], bfr[j], acc[i][j], 0, 0, 0);
        }
    }
    #pragma unroll
    for (int j = 0; j < 4; j++) {
        int n = n0 + wn + j * 16 + c16;
        unsigned short* dst = C + (size_t)n * CHN;
        #pragma unroll
        for (int i = 0; i < 4; i++) {
            int m = m0 + wm + i * 16 + quad * 4;
            if (m < CHN) {
                short4v sv;
                sv[0] = (short)f2bf(acc[i][j][0]);
                sv[1] = (short)f2bf(acc[i][j][1]);
                sv[2] = (short)f2bf(acc[i][j][2]);
                sv[3] = (short)f2bf(acc[i][j][3]);
                *(short4v*)(dst + m) = sv;
            }
        }
    }
}

// ---------------- fused tvconv + gelu-gate: XCD-affinity swizzled grid ----------------
__global__ __launch_bounds__(256) void k_tvg(const unsigned short* __restrict__ h1t,
                                             const unsigned short* __restrict__ wgtT,
                                             unsigned short* __restrict__ hgt) {
    __shared__ __align__(16) unsigned short wl[9 * CHN];   // 24480 B, [k][CHN]
    int id = blockIdx.x;
    int xcd = id & 7, q = id >> 3;
    int p = xcd * 25 + (q % 25);
    int bg = q / 25;
    if (p >= P) return;
    int b0 = bg * 16, tid = threadIdx.x;
    const unsigned short* wrow = wgtT + (size_t)p * 9 * CHN;
    for (int i = tid * 8; i < 9 * CHN; i += 256 * 8)
        *(short8*)(wl + i) = *(const short8*)(wrow + i);
    int y = p / WP, x = p - (p / WP) * WP;
    int pn[9]; bool pv[9];
    #pragma unroll
    for (int k = 0; k < 9; k++) {
        int yy = y + k / 3 - 1, xx = x + (k % 3) - 1;
        pv[k] = (yy >= 0 && yy < HP && xx >= 0 && xx < WP);
        pn[k] = pv[k] ? yy * WP + xx : 0;
    }
    __syncthreads();
    for (int j = tid; j < 16 * 85; j += 256) {
        int bl = j / 85, c = (j - bl * 85) * 8;
        int b = b0 + bl;
        const unsigned short* hb = h1t + (size_t)b * P * CHN;
        float s1[8], s2[8];
        #pragma unroll
        for (int e = 0; e < 8; e++) { s1[e] = 0.f; s2[e] = 0.f; }
        #pragma unroll
        for (int k = 0; k < 9; k++) {
            if (!pv[k]) continue;
            const unsigned short* hr = hb + (size_t)pn[k] * CHN + c;
            short8 h1v = *(const short8*)hr;
            short8 h2v = *(const short8*)(hr + HID);
            short8 w1v = *(const short8*)(wl + k * CHN + c);
            short8 w2v = *(const short8*)(wl + k * CHN + HID + c);
            #pragma unroll
            for (int e = 0; e < 8; e++) {
                s1[e] += bf2f((unsigned short)w1v[e]) * bf2f((unsigned short)h1v[e]);
                s2[e] += bf2f((unsigned short)w2v[e]) * bf2f((unsigned short)h2v[e]);
            }
        }
        short8 o;
        #pragma unroll
        for (int e = 0; e < 8; e++) {
            float gl = 0.5f * s1[e] * (1.f + erff(s1[e] * 0.70710678118654752f));
            o[e] = (short)f2bf(gl * s2[e]);
        }
        *(short8*)(hgt + ((size_t)b * P + p) * KPAD + c) = o;
    }
    if (tid < 48) {
        int bl = tid / 3, z = (tid - bl * 3) * 8;
        *(short8*)(hgt + ((size_t)(b0 + bl) * P + p) * KPAD + HID + z) = (short8)0;
    }
}

// ---------------- tiled MFMA GEMM 2 (BK=64): out[m][n] = sum_k Wbout[m][k] hgt[n][k] ------
__global__ __launch_bounds__(256) void k_gemm_out(const unsigned short* __restrict__ A,
                                                  const unsigned short* __restrict__ B,
                                                  float* __restrict__ out) {
    __shared__ __align__(16) unsigned short As[64 * 64];     // 8 KB
    __shared__ __align__(16) unsigned short Bs[128 * 64];    // 16 KB
    int tid = threadIdx.x;
    int w = tid >> 6, lane = tid & 63, quad = lane >> 4, c16 = lane & 15;
    int m0 = blockIdx.x * 64, n0 = blockIdx.y * 128;
    int wm = (w & 1) * 32, wn = (w >> 1) * 64;
    f32x4 acc[2][4];
    #pragma unroll
    for (int i = 0; i < 2; i++)
        #pragma unroll
        for (int j = 0; j < 4; j++) acc[i][j] = (f32x4)0.f;

    for (int kc = 0; kc < 11; ++kc) {                        // K=704, chunks of 64
        int k0 = kc * 64;
        if (kc) __syncthreads();
        #pragma unroll
        for (int i = tid; i < 512; i += 256) {               // A: 64 rows x 8 pieces
            int r = i >> 3, s = i & 7, q = (s - (r >> 1)) & 7;
            gl2lds16(A + (size_t)(m0 + r) * KPAD + k0 + q * 8, As + (i & ~63) * 8);
        }
        #pragma unroll
        for (int i = tid; i < 1024; i += 256) {              // B: 128 rows x 8 pieces
            int r = i >> 3, s = i & 7, q = (s - (r >> 1)) & 7;
            gl2lds16(B + (size_t)(n0 + r) * KPAD + k0 + q * 8, Bs + (i & ~63) * 8);
        }
        __syncthreads();
        #pragma unroll
        for (int ks = 0; ks < 2; ++ks) {
            short8 af[2], bfr[4];
            #pragma unroll
            for (int i = 0; i < 2; i++) af[i] = fragld64(As, wm + i * 16 + c16, ks * 4 + quad);
            #pragma unroll
            for (int j = 0; j < 4; j++) bfr[j] = fragld64(Bs, wn + j * 16 + c16, ks * 4 + quad);
            #pragma unroll
            for (int i = 0; i < 2; i++)
                #pragma unroll
                for (int j = 0; j < 4; j++)
                    acc[i][j] = __builtin_amdgcn_mfma_f32_16x16x32_bf16(af[i], bfr[j], acc[i][j], 0, 0, 0);
        }
    }
    #pragma unroll
    for (int j = 0; j < 4; j++) {
        int n = n0 + wn + j * 16 + c16;
        int b = n / P, pp = n - b * P;
        #pragma unroll
        for (int i = 0; i < 2; i++) {
            int m = m0 + wm + i * 16 + quad * 4;
            #pragma unroll
            for (int r = 0; r < 4; r++)
                out[((size_t)b * DIMC + m + r) * P + pp] = acc[i][j][r];
        }
    }
}

extern "C" void kernel_launch(void* const* d_in, const int* in_sizes, int n_in,
                              void* d_out, int out_size, void* d_ws, size_t ws_size,
                              hipStream_t stream) {
    (void)in_sizes; (void)n_in; (void)out_size; (void)ws_size;
    const float* x     = (const float*)d_in[0];
    const float* W_in  = (const float*)d_in[1];
    const float* posi  = (const float*)d_in[2];
    const float* w0    = (const float*)d_in[3];
    const float* g0    = (const float*)d_in[4];
    const float* b0    = (const float*)d_in[5];
    const float* w1    = (const float*)d_in[6];
    const float* g1    = (const float*)d_in[7];
    const float* b1    = (const float*)d_in[8];
    const float* w2    = (const float*)d_in[9];
    const float* g2    = (const float*)d_in[10];
    const float* b2    = (const float*)d_in[11];
    const float* wf    = (const float*)d_in[12];
    const float* W_out = (const float*)d_in[13];
    float* out = (float*)d_out;
    char* ws = (char*)d_ws;

    unsigned short* Wbin  = (unsigned short*)(ws + OFS_WBIN);
    unsigned short* Wbout = (unsigned short*)(ws + OFS_WBOUT);
    unsigned short* Xt    = (unsigned short*)(ws + OFS_XT);
    float*          a_buf = (float*)(ws + OFS_ABUF);
    float*          v1    = (float*)(ws + OFS_V1);
    float*          v2    = (float*)(ws + OFS_V2);
    float*          stats = (float*)(ws + OFS_STAT);
    unsigned short* wgtT  = (unsigned short*)(ws + OFS_WGTT);
    unsigned short* h1t   = (unsigned short*)(ws + OFS_H1T);
    unsigned short* hgt   = (unsigned short*)(ws + OFS_HGT);
    unsigned short* imc   = (unsigned short*)(ws + OFS_IMC);
    unsigned short* wfb   = (unsigned short*)(ws + OFS_WFB);

    // 1: fused preamble (casts, x-transpose, wf transpose/cast, imc zero, stage0, stats=0)
    k_pre<<<PRE_CAST_BLKS + PRE_XT_BLKS + PRE_WF_BLKS + PRE_IMZ_BLKS + 1, 256, 0, stream>>>(
        W_in, W_out, x, wf, posi, w0, g0, b0, Wbin, Wbout, Xt, wfb, imc, a_buf, stats);
    // 2-4: weight-generator chain (kernel-boundary sync)
    k_conv1<<<49, 256, 0, stream>>>(a_buf, w1, v1, stats);
    k_conv2<<<49, 256, 0, stream>>>(v1, g1, b1, w2, v2, stats);
    k_lnsc <<<49, 256, 0, stream>>>(v2, g2, b2, stats, imc);
    // 5: final conv GEMM (bf16 A, BK=64)
    k_gemm_wf<<<MTOT/64, 256, 0, stream>>>(wfb, imc, wgtT);
    // 6-8: main path
    k_gemm_in <<<dim3(MPADIN/128, (BATCH*P)/128), 256, 0, stream>>>(Wbin, Xt, h1t);
    k_tvg     <<<800, 256, 0, stream>>>(h1t, wgtT, hgt);
    k_gemm_out<<<dim3(DIMC/64, (BATCH*P)/128), 256, 0, stream>>>(Wbout, hgt, out);
}